// Round 4
// baseline (842.538 us; speedup 1.0000x reference)
//
#include <hip/hip_runtime.h>
#include <hip/hip_fp16.h>

#define HH 512
#define WW 512
#define NB 8
#define TS 16
#define LROW 19
#define LPLANE (18*LROW)
#define PROW 72            // bf16 channels per pbuf row (144 B, 16B-aligned)

typedef unsigned int u32;
typedef __attribute__((ext_vector_type(8))) short bf16x8;
typedef __attribute__((ext_vector_type(4))) float f32x4;

// ---------------- threefry2x32 core ----------------
__device__ __forceinline__ u32 rotl32(u32 v, int n){ return (v<<n)|(v>>(32-n)); }
struct U2 { u32 x, y; };

__device__ __forceinline__ U2 threefry2x32(u32 k0, u32 k1, u32 x0, u32 x1){
  u32 k2 = k0 ^ k1 ^ 0x1BD11BDAu;
  x0 += k0; x1 += k1;
  const int RA[4] = {13,15,26,6};
  const int RB[4] = {17,29,16,24};
  #pragma unroll
  for(int i=0;i<4;i++){ x0+=x1; x1=rotl32(x1,RA[i]); x1^=x0; }
  x0 += k1; x1 += k2 + 1u;
  #pragma unroll
  for(int i=0;i<4;i++){ x0+=x1; x1=rotl32(x1,RB[i]); x1^=x0; }
  x0 += k2; x1 += k0 + 2u;
  #pragma unroll
  for(int i=0;i<4;i++){ x0+=x1; x1=rotl32(x1,RA[i]); x1^=x0; }
  x0 += k0; x1 += k1 + 3u;
  #pragma unroll
  for(int i=0;i<4;i++){ x0+=x1; x1=rotl32(x1,RB[i]); x1^=x0; }
  x0 += k1; x1 += k2 + 4u;
  #pragma unroll
  for(int i=0;i<4;i++){ x0+=x1; x1=rotl32(x1,RA[i]); x1^=x0; }
  x0 += k2; x1 += k0 + 5u;
  U2 r; r.x = x0; r.y = x1; return r;
}

// partitionable draw (modern JAX default): counter=(0,i), out = x^y
__device__ __forceinline__ u32 pbits(u32 k0, u32 k1, u32 i){
  U2 o = threefry2x32(k0, k1, 0u, i);
  return o.x ^ o.y;
}

__device__ __forceinline__ float xla_erfinv(float x){
  float w = -log1pf(-x*x);
  float p;
  if (w < 5.0f){
    w -= 2.5f;
    p = 2.81022636e-08f;
    p = fmaf(p,w, 3.43273939e-07f);
    p = fmaf(p,w,-3.5233877e-06f);
    p = fmaf(p,w,-4.39150654e-06f);
    p = fmaf(p,w, 0.00021858087f);
    p = fmaf(p,w,-0.00125372503f);
    p = fmaf(p,w,-0.00417768164f);
    p = fmaf(p,w, 0.246640727f);
    p = fmaf(p,w, 1.50140941f);
  } else {
    w = sqrtf(w) - 3.0f;
    p = -0.000200214257f;
    p = fmaf(p,w, 0.000100950558f);
    p = fmaf(p,w, 0.00134934322f);
    p = fmaf(p,w,-0.00367342844f);
    p = fmaf(p,w, 0.00573950773f);
    p = fmaf(p,w,-0.0076224613f);
    p = fmaf(p,w, 0.00943887047f);
    p = fmaf(p,w, 1.00167406f);
    p = fmaf(p,w, 2.83297682f);
  }
  return p*x;
}

__device__ __forceinline__ float normal_from_bits(u32 bits){
  const float LO = -0.99999994f;
  u32 fb = (bits >> 9) | 0x3F800000u;
  float f = __uint_as_float(fb) - 1.0f;
  float u = f * 2.0f + LO;
  u = fmaxf(LO, u);
  return 1.41421356f * xla_erfinv(u);
}

// foldlike split (partitionable)
__device__ __forceinline__ void noise_keys(int seed, u32& k1a, u32& k1b, u32& k2a, u32& k2b){
  u32 K0 = 0u, K1 = (u32)seed;
  U2 nk = threefry2x32(K0, K1, 0u, 1u);
  U2 c1 = threefry2x32(nk.x, nk.y, 0u, 0u);
  U2 c2 = threefry2x32(nk.x, nk.y, 0u, 1u);
  k1a = c1.x; k1b = c1.y;
  k2a = c2.x; k2b = c2.y;
}

// RNE f32->bf16
__device__ __forceinline__ unsigned short f2bf(float f){
  u32 x = __float_as_uint(f);
  u32 r = x + 0x7FFFu + ((x >> 16) & 1u);
  return (unsigned short)(r >> 16);
}
__device__ __forceinline__ u32 pack2bf(float a, float b){
  return (u32)f2bf(a) | ((u32)f2bf(b) << 16);
}

// ---------------- prep: weights -> B-fragment order (bf16) ----------------
// frag layout per MFMA 16x16x32 B-operand: lane L: n = (L&15), k = (L>>4)*8+j
// f 0..7  : layer1, f = kh*4+nc  (k = kh*32+..., n = nc*16+...)
// f 8..11 : layer2, f = 8+kh*2+nc
// f 12    : heads packed N=16: cols [rgb0..2, 0, vel0..1, 0, 0, hid0..7]
__global__ void prep_w(const float* __restrict__ w1, const float* __restrict__ w2,
                       const float* __restrict__ wrgb, const float* __restrict__ wvel,
                       const float* __restrict__ whid,
                       const float* __restrict__ brgb, const float* __restrict__ bvel,
                       const float* __restrict__ bhid,
                       unsigned short* __restrict__ wfrag, float* __restrict__ bcat){
  int tid = threadIdx.x;
  for (int f = tid >> 6; f < 13; f += 4){
    int lane = tid & 63, quad = lane >> 4, m = lane & 15;
    #pragma unroll
    for (int j = 0; j < 8; ++j){
      float val;
      if (f < 8){
        int kh = f >> 2, nc = f & 3;
        int k = kh*32 + quad*8 + j, n = nc*16 + m;
        val = w1[k*64 + n];
      } else if (f < 12){
        int g = f - 8, kh = g >> 1, nc = g & 1;
        int k = kh*32 + quad*8 + j, n = nc*16 + m;
        val = w2[k*32 + n];
      } else {
        int k = quad*8 + j;
        val = (m < 3) ? wrgb[k*3 + m]
            : (m == 4 || m == 5) ? wvel[k*2 + (m-4)]
            : (m >= 8) ? whid[k*8 + (m-8)] : 0.0f;
      }
      wfrag[(f*64 + lane)*8 + j] = f2bf(val);
    }
  }
  if (tid < 16)
    bcat[tid] = (tid < 3) ? brgb[tid]
              : (tid == 4 || tid == 5) ? bvel[tid-4]
              : (tid >= 8) ? bhid[tid-8] : 0.0f;
}

// ---------------- kernel A: stencil + MFMA MLP + epilogue ----------------
__global__ __launch_bounds__(256, 2) void nca_main(
    const float* __restrict__ st, const int* __restrict__ seedp,
    const float* __restrict__ b1, const float* __restrict__ b2,
    const unsigned short* __restrict__ wfrag, const float* __restrict__ bcat,
    float* __restrict__ out, u32* __restrict__ vxy, float* __restrict__ m0p)
{
  __shared__ float ls[16][LPLANE];                         // 21888 B
  __shared__ __align__(16) unsigned short pbuf[256*PROW];  // 36864 B

  const int tid  = threadIdx.x;
  const int lane = tid & 63, wv = tid >> 6;
  const int quad = lane >> 4, mm = lane & 15;
  const int bx = blockIdx.x, by = blockIdx.y, b = blockIdx.z;
  const int x0t = bx*TS, y0t = by*TS;
  const float* __restrict__ sb = st + (size_t)b*HH*WW*16;

  // B fragments + biases (L2-hot)
  bf16x8 Bf[13];
  #pragma unroll
  for (int f = 0; f < 13; ++f)
    Bf[f] = *(const bf16x8*)(wfrag + (f*64 + lane)*8);
  float bias1[4], bias2[2];
  #pragma unroll
  for (int nc = 0; nc < 4; ++nc) bias1[nc] = b1[nc*16 + mm];
  #pragma unroll
  for (int nc = 0; nc < 2; ++nc) bias2[nc] = b2[nc*16 + mm];
  float biasH = bcat[mm];

  // stage 18x18 x 16ch state tile
  for (int t = tid; t < 18*18*4; t += 256){
    int pix = t >> 2, part = t & 3;
    int py = pix / 18, px = pix - py*18;
    int gy = (y0t + py - 1) & (HH-1);
    int gx = (x0t + px - 1) & (WW-1);
    const float4 v = *(const float4*)(sb + ((gy*WW + gx)*16 + part*4));
    int li = py*LROW + px;
    ls[part*4+0][li] = v.x; ls[part*4+1][li] = v.y;
    ls[part*4+2][li] = v.z; ls[part*4+3][li] = v.w;
  }
  __syncthreads();

  const int lx = tid & 15, ly = tid >> 4;
  const int ctr = (ly+1)*LROW + (lx+1);

  // ---- perception (f32, exact) -> bf16 pbuf[px=tid][ch] ----
  float p[64];
  #pragma unroll
  for (int c = 0; c < 16; ++c){
    const float* __restrict__ pl = ls[c];
    float id = pl[ctr];
    float gx = (pl[ctr-LROW+1] + 2.0f*pl[ctr+1] + pl[ctr+LROW+1]
              - pl[ctr-LROW-1] - 2.0f*pl[ctr-1] - pl[ctr+LROW-1]) * 0.125f;
    float gy = (pl[ctr+LROW-1] + 2.0f*pl[ctr+LROW] + pl[ctr+LROW+1]
              - pl[ctr-LROW-1] - 2.0f*pl[ctr-LROW] - pl[ctr-LROW+1]) * 0.125f;
    float lp = (pl[ctr+1] + pl[ctr-1] + pl[ctr+LROW] + pl[ctr-LROW]
              - 4.0f*pl[ctr]) * 0.25f;
    p[c] = id; p[16+c] = gx; p[32+c] = gy; p[48+c] = lp;
  }
  {
    u32* pb32 = (u32*)pbuf;
    #pragma unroll
    for (int i = 0; i < 32; ++i){
      int c = (i + tid) & 31;                 // rotation -> conflict-free
      pb32[tid*(PROW/2) + c] = pack2bf(p[2*c], p[2*c+1]);
    }
  }
  __syncthreads();

  const int rowbase = wv*4;   // each wave owns 4 pixel-rows (groups)

  // ---- layer 1: x1 = relu(p @ w1 + b1) ----
  f32x4 C1[4][4];
  #pragma unroll
  for (int gi = 0; gi < 4; ++gi){
    const unsigned short* ar = pbuf + ((rowbase+gi)*16 + mm)*PROW + quad*8;
    bf16x8 a0 = *(const bf16x8*)(ar);
    bf16x8 a1 = *(const bf16x8*)(ar + 32);
    #pragma unroll
    for (int nc = 0; nc < 4; ++nc){
      f32x4 c; c[0]=bias1[nc]; c[1]=bias1[nc]; c[2]=bias1[nc]; c[3]=bias1[nc];
      c = __builtin_amdgcn_mfma_f32_16x16x32_bf16(a0, Bf[nc],   c, 0,0,0);
      c = __builtin_amdgcn_mfma_f32_16x16x32_bf16(a1, Bf[4+nc], c, 0,0,0);
      C1[gi][nc] = c;
    }
  }
  __syncthreads();
  #pragma unroll
  for (int gi = 0; gi < 4; ++gi)
    #pragma unroll
    for (int nc = 0; nc < 4; ++nc)
      #pragma unroll
      for (int r = 0; r < 4; ++r)
        pbuf[((rowbase+gi)*16 + quad*4 + r)*PROW + nc*16 + mm] =
            f2bf(fmaxf(C1[gi][nc][r], 0.0f));
  __syncthreads();

  // ---- layer 2: x2 = relu(x1 @ w2 + b2) ----
  f32x4 C2[4][2];
  #pragma unroll
  for (int gi = 0; gi < 4; ++gi){
    const unsigned short* ar = pbuf + ((rowbase+gi)*16 + mm)*PROW + quad*8;
    bf16x8 a0 = *(const bf16x8*)(ar);
    bf16x8 a1 = *(const bf16x8*)(ar + 32);
    #pragma unroll
    for (int nc = 0; nc < 2; ++nc){
      f32x4 c; c[0]=bias2[nc]; c[1]=bias2[nc]; c[2]=bias2[nc]; c[3]=bias2[nc];
      c = __builtin_amdgcn_mfma_f32_16x16x32_bf16(a0, Bf[8+nc],  c, 0,0,0);
      c = __builtin_amdgcn_mfma_f32_16x16x32_bf16(a1, Bf[10+nc], c, 0,0,0);
      C2[gi][nc] = c;
    }
  }
  __syncthreads();
  #pragma unroll
  for (int gi = 0; gi < 4; ++gi)
    #pragma unroll
    for (int nc = 0; nc < 2; ++nc)
      #pragma unroll
      for (int r = 0; r < 4; ++r)
        pbuf[((rowbase+gi)*16 + quad*4 + r)*PROW + nc*16 + mm] =
            f2bf(fmaxf(C2[gi][nc][r], 0.0f));
  __syncthreads();

  // ---- heads: ds16 = x2 @ Wcat + bcat (cols 3,6,7 zero) ----
  f32x4 C3[4];
  #pragma unroll
  for (int gi = 0; gi < 4; ++gi){
    const unsigned short* ar = pbuf + ((rowbase+gi)*16 + mm)*PROW + quad*8;
    bf16x8 a0 = *(const bf16x8*)(ar);
    f32x4 c; c[0]=biasH; c[1]=biasH; c[2]=biasH; c[3]=biasH;
    C3[gi] = __builtin_amdgcn_mfma_f32_16x16x32_bf16(a0, Bf[12], c, 0,0,0);
  }
  __syncthreads();
  {
    float* dsb = (float*)pbuf;   // 256 x 17 f32 = 17408 B, fits in pbuf
    #pragma unroll
    for (int gi = 0; gi < 4; ++gi)
      #pragma unroll
      for (int r = 0; r < 4; ++r)
        dsb[((rowbase+gi)*16 + quad*4 + r)*17 + mm] = C3[gi][r];
  }
  __syncthreads();

  // ---- epilogue (exact f32): mask, clips, writes; thread = pixel ----
  const float* dsb = (const float*)pbuf;
  int seed = seedp[0];
  u32 K0 = 0u, K1 = (u32)seed;
  const int ygl = y0t + ly, xgl = x0t + lx;
  const u32 pix = ((u32)b*HH + ygl)*WW + xgl;
  u32 mbits = pbits(K0, K1, pix);
  float m = ((int)mbits >= 0) ? 1.0f : 0.0f;

  float sc[16], ds[16], ns[16];
  #pragma unroll
  for (int ch = 0; ch < 16; ++ch) sc[ch] = ls[ch][ctr];
  #pragma unroll
  for (int ch = 0; ch < 16; ++ch) ds[ch] = dsb[tid*17 + ch];
  #pragma unroll
  for (int ch = 0; ch < 16; ++ch) ns[ch] = sc[ch] + ds[ch]*m;

  ns[4] = 0.95f * fminf(fmaxf(ns[4], -1.0f), 1.0f);
  ns[5] = 0.95f * fminf(fmaxf(ns[5], -1.0f), 1.0f);
  ns[0] = fminf(fmaxf(ns[0], 0.0f), 1.0f);
  ns[1] = fminf(fmaxf(ns[1], 0.0f), 1.0f);
  ns[2] = fminf(fmaxf(ns[2], 0.0f), 1.0f);
  ns[3] = sc[3];

  float* __restrict__ op = out + (size_t)pix*16;
  *(float4*)(op+ 0) = make_float4(ns[0],ns[1],ns[2],ns[3]);
  *(float4*)(op+ 4) = make_float4(ns[4],ns[5],ns[6],ns[7]);
  *(float4*)(op+ 8) = make_float4(ns[8],ns[9],ns[10],ns[11]);
  *(float4*)(op+12) = make_float4(ns[12],ns[13],ns[14],ns[15]);

  u32 k1a,k1b,k2a,k2b; noise_keys(seed, k1a,k1b,k2a,k2b);
  float vx = ns[4] + 0.2f*normal_from_bits(pbits(k1a,k1b,pix));
  float vy = ns[5] + 0.2f*normal_from_bits(pbits(k2a,k2b,pix));
  __half2 hv = __floats2half2_rn(vx, vy);
  vxy[pix] = *(u32*)&hv;
  m0p[pix] = sc[3];
}

// ---------------- advection ----------------
__device__ __forceinline__ float bilin(const float* __restrict__ mp,
                                       float yy, float xx, float vx, float vy){
  float sy = yy - vy*0.25f;
  float sx = xx - vx*0.25f;
  float y0f = floorf(sy), x0f = floorf(sx);
  float fy = sy - y0f,   fx = sx - x0f;
  int y0 = ((int)y0f) & 511, x0 = ((int)x0f) & 511;
  int y1 = (y0+1) & 511,     x1 = (x0+1) & 511;
  float m00 = mp[(y0<<9)+x0], m01 = mp[(y0<<9)+x1];
  float m10 = mp[(y1<<9)+x0], m11 = mp[(y1<<9)+x1];
  return (1.0f-fy)*((1.0f-fx)*m00 + fx*m01) + fy*((1.0f-fx)*m10 + fx*m11);
}

__global__ __launch_bounds__(256) void advect_k(
    const float* __restrict__ msrc, const u32* __restrict__ vxy,
    float* __restrict__ mdst)
{
  int i = blockIdx.x*256 + threadIdx.x;
  int b = i >> 18; int rem = i & 0x3FFFF; int y = rem >> 9; int x = rem & 511;
  u32 v = vxy[i];
  __half2 hv = *(__half2*)&v;
  float vx = __low2float(hv), vy = __high2float(hv);
  const float* mb = msrc + (((size_t)b)<<18);
  mdst[i] = bilin(mb, (float)y, (float)x, vx, vy);
}

__global__ __launch_bounds__(256) void diffuse_k(
    const float* __restrict__ m2, float* __restrict__ out)
{
  int i = blockIdx.x*256 + threadIdx.x;
  int b = i >> 18; int rem = i & 0x3FFFF; int y = rem >> 9; int x = rem & 511;
  const float* mb = m2 + (((size_t)b)<<18);
  float c = mb[(y<<9)+x];
  float r = mb[(y<<9)+((x+1)&511)];
  float l = mb[(y<<9)+((x-1)&511)];
  float d = mb[(((y+1)&511)<<9)+x];
  float u = mb[(((y-1)&511)<<9)+x];
  out[(size_t)i*16 + 3] = c + 0.05f*((r+l+d+u)*0.25f - c);
}

// ---------------- launch ----------------
extern "C" void kernel_launch(void* const* d_in, const int* in_sizes, int n_in,
                              void* d_out, int out_size, void* d_ws, size_t ws_size,
                              hipStream_t stream)
{
  const float* st   = (const float*)d_in[0];
  const int*   seed = (const int*)  d_in[1];
  const float* w1   = (const float*)d_in[2];
  const float* b1   = (const float*)d_in[3];
  const float* w2   = (const float*)d_in[4];
  const float* b2   = (const float*)d_in[5];
  const float* wrgb = (const float*)d_in[6];
  const float* brgb = (const float*)d_in[7];
  const float* wvel = (const float*)d_in[8];
  const float* bvel = (const float*)d_in[9];
  const float* whid = (const float*)d_in[10];
  const float* bhid = (const float*)d_in[11];
  float* out = (float*)d_out;

  const int npix = NB*HH*WW;                 // 2^21
  float* m0p = (float*)d_ws;                 // 8 MB (m0, then reused as m2)
  float* m1p = m0p + npix;                   // 8 MB
  u32*   vxy = (u32*)(m1p + npix);           // 8 MB (f16x2 packed vel)
  unsigned short* wfrag = (unsigned short*)(vxy + npix);  // 13312 B
  float* bcat = (float*)(wfrag + 13*64*8);   // 64 B

  prep_w<<<1, 256, 0, stream>>>(w1, w2, wrgb, wvel, whid, brgb, bvel, bhid, wfrag, bcat);

  dim3 gridA(WW/TS, HH/TS, NB);
  nca_main<<<gridA, 256, 0, stream>>>(st, seed, b1, b2, wfrag, bcat, out, vxy, m0p);

  advect_k<<<npix/256, 256, 0, stream>>>(m0p, vxy, m1p);   // step 1: m0 -> m1
  advect_k<<<npix/256, 256, 0, stream>>>(m1p, vxy, m0p);   // step 2: m1 -> m2 (reuse m0p)
  diffuse_k<<<npix/256, 256, 0, stream>>>(m0p, out);
}

// Round 5
// 413.532 us; speedup vs baseline: 2.0374x; 2.0374x over previous
//
#include <hip/hip_runtime.h>
#include <hip/hip_fp16.h>

#define HH 512
#define WW 512
#define NB 8
#define TS 16
#define LROW 19
#define LPLANE (18*LROW)
#define PROW 68            // f16 channels per pbuf row (136 B = 34 dwords -> 2-way banks)

typedef unsigned int u32;
typedef __attribute__((ext_vector_type(4))) _Float16 f16x4;
typedef __attribute__((ext_vector_type(8))) _Float16 f16x8;
typedef __attribute__((ext_vector_type(4))) float f32x4;

// ---------------- threefry2x32 core ----------------
__device__ __forceinline__ u32 rotl32(u32 v, int n){ return (v<<n)|(v>>(32-n)); }
struct U2 { u32 x, y; };

__device__ __forceinline__ U2 threefry2x32(u32 k0, u32 k1, u32 x0, u32 x1){
  u32 k2 = k0 ^ k1 ^ 0x1BD11BDAu;
  x0 += k0; x1 += k1;
  const int RA[4] = {13,15,26,6};
  const int RB[4] = {17,29,16,24};
  #pragma unroll
  for(int i=0;i<4;i++){ x0+=x1; x1=rotl32(x1,RA[i]); x1^=x0; }
  x0 += k1; x1 += k2 + 1u;
  #pragma unroll
  for(int i=0;i<4;i++){ x0+=x1; x1=rotl32(x1,RB[i]); x1^=x0; }
  x0 += k2; x1 += k0 + 2u;
  #pragma unroll
  for(int i=0;i<4;i++){ x0+=x1; x1=rotl32(x1,RA[i]); x1^=x0; }
  x0 += k0; x1 += k1 + 3u;
  #pragma unroll
  for(int i=0;i<4;i++){ x0+=x1; x1=rotl32(x1,RB[i]); x1^=x0; }
  x0 += k1; x1 += k2 + 4u;
  #pragma unroll
  for(int i=0;i<4;i++){ x0+=x1; x1=rotl32(x1,RA[i]); x1^=x0; }
  x0 += k2; x1 += k0 + 5u;
  U2 r; r.x = x0; r.y = x1; return r;
}

// partitionable draw (modern JAX default): counter=(0,i), out = x^y
__device__ __forceinline__ u32 pbits(u32 k0, u32 k1, u32 i){
  U2 o = threefry2x32(k0, k1, 0u, i);
  return o.x ^ o.y;
}

__device__ __forceinline__ float xla_erfinv(float x){
  float w = -log1pf(-x*x);
  float p;
  if (w < 5.0f){
    w -= 2.5f;
    p = 2.81022636e-08f;
    p = fmaf(p,w, 3.43273939e-07f);
    p = fmaf(p,w,-3.5233877e-06f);
    p = fmaf(p,w,-4.39150654e-06f);
    p = fmaf(p,w, 0.00021858087f);
    p = fmaf(p,w,-0.00125372503f);
    p = fmaf(p,w,-0.00417768164f);
    p = fmaf(p,w, 0.246640727f);
    p = fmaf(p,w, 1.50140941f);
  } else {
    w = sqrtf(w) - 3.0f;
    p = -0.000200214257f;
    p = fmaf(p,w, 0.000100950558f);
    p = fmaf(p,w, 0.00134934322f);
    p = fmaf(p,w,-0.00367342844f);
    p = fmaf(p,w, 0.00573950773f);
    p = fmaf(p,w,-0.0076224613f);
    p = fmaf(p,w, 0.00943887047f);
    p = fmaf(p,w, 1.00167406f);
    p = fmaf(p,w, 2.83297682f);
  }
  return p*x;
}

__device__ __forceinline__ float normal_from_bits(u32 bits){
  const float LO = -0.99999994f;
  u32 fb = (bits >> 9) | 0x3F800000u;
  float f = __uint_as_float(fb) - 1.0f;
  float u = f * 2.0f + LO;
  u = fmaxf(LO, u);
  return 1.41421356f * xla_erfinv(u);
}

// foldlike split (partitionable)
__device__ __forceinline__ void noise_keys(int seed, u32& k1a, u32& k1b, u32& k2a, u32& k2b){
  u32 K0 = 0u, K1 = (u32)seed;
  U2 nk = threefry2x32(K0, K1, 0u, 1u);
  U2 c1 = threefry2x32(nk.x, nk.y, 0u, 0u);
  U2 c2 = threefry2x32(nk.x, nk.y, 0u, 1u);
  k1a = c1.x; k1b = c1.y;
  k2a = c2.x; k2b = c2.y;
}

__device__ __forceinline__ u32 h2_as_u32(__half2 h){ return *(u32*)&h; }
__device__ __forceinline__ __half2 u32_as_h2(u32 v){ return *(__half2*)&v; }

// ---------------- prep: weights -> B-fragment order (f16) ----------------
// B-frag 16x16x32: lane L: n=(L&15), k=(L>>4)*8+j
// f 0..7: layer1 (f=kh*4+nc); f 8..11: layer2 (f=8+kh*2+nc); f 12: heads N=16
__global__ void prep_w(const float* __restrict__ w1, const float* __restrict__ w2,
                       const float* __restrict__ wrgb, const float* __restrict__ wvel,
                       const float* __restrict__ whid,
                       const float* __restrict__ brgb, const float* __restrict__ bvel,
                       const float* __restrict__ bhid,
                       unsigned short* __restrict__ wfrag, float* __restrict__ bcat){
  int tid = threadIdx.x;
  for (int f = tid >> 6; f < 13; f += 4){
    int lane = tid & 63, quad = lane >> 4, m = lane & 15;
    #pragma unroll
    for (int j = 0; j < 8; ++j){
      float val;
      if (f < 8){
        int kh = f >> 2, nc = f & 3;
        int k = kh*32 + quad*8 + j, n = nc*16 + m;
        val = w1[k*64 + n];
      } else if (f < 12){
        int g = f - 8, kh = g >> 1, nc = g & 1;
        int k = kh*32 + quad*8 + j, n = nc*16 + m;
        val = w2[k*32 + n];
      } else {
        int k = quad*8 + j;
        val = (m < 3) ? wrgb[k*3 + m]
            : (m == 4 || m == 5) ? wvel[k*2 + (m-4)]
            : (m >= 8) ? whid[k*8 + (m-8)] : 0.0f;
      }
      wfrag[(f*64 + lane)*8 + j] = __half_as_ushort(__float2half(val));
    }
  }
  if (tid < 16)
    bcat[tid] = (tid < 3) ? brgb[tid]
              : (tid == 4 || tid == 5) ? bvel[tid-4]
              : (tid >= 8) ? bhid[tid-8] : 0.0f;
}

// ---------------- kernel A: f16 stencil + f16 MFMA MLP + exact-f32 epilogue ----------------
__global__ __launch_bounds__(256, 4) void nca_main(
    const float* __restrict__ st, const int* __restrict__ seedp,
    const float* __restrict__ b1, const float* __restrict__ b2,
    const unsigned short* __restrict__ wfrag, const float* __restrict__ bcat,
    float* __restrict__ out, u32* __restrict__ vxy, float* __restrict__ m0p)
{
  // union: stage planes (8 x LPLANE u32 = 10944 B) then pbuf (256*68*2 = 34816 B)
  __shared__ __align__(16) unsigned char smem[256*PROW*2];
  u32 (*ls2)[LPLANE] = (u32 (*)[LPLANE])smem;          // 8 planes of half2 ch-pairs
  unsigned short* pbuf = (unsigned short*)smem;

  const int tid  = threadIdx.x;
  const int lane = tid & 63, wv = tid >> 6;
  const int quad = lane >> 4, mm = lane & 15;
  const int bx = blockIdx.x, by = blockIdx.y, b = blockIdx.z;
  const int x0t = bx*TS, y0t = by*TS;
  const float* __restrict__ sb = st + (size_t)b*HH*WW*16;

  // B fragments + biases (L2-hot)
  f16x8 Bf[13];
  #pragma unroll
  for (int f = 0; f < 13; ++f)
    Bf[f] = *(const f16x8*)(wfrag + (f*64 + lane)*8);
  float bias1[4], bias2[2];
  #pragma unroll
  for (int nc = 0; nc < 4; ++nc) bias1[nc] = b1[nc*16 + mm];
  #pragma unroll
  for (int nc = 0; nc < 2; ++nc) bias2[nc] = b2[nc*16 + mm];
  float biasH = bcat[mm];

  // stage 18x18 px x 8 half2-pairs
  for (int t = tid; t < 18*18*4; t += 256){
    int pix = t >> 2, part = t & 3;
    int py = pix / 18, px = pix - py*18;
    int gy = (y0t + py - 1) & (HH-1);
    int gx = (x0t + px - 1) & (WW-1);
    const float4 v = *(const float4*)(sb + ((gy*WW + gx)*16 + part*4));
    int li = py*LROW + px;
    ls2[part*2  ][li] = h2_as_u32(__floats2half2_rn(v.x, v.y));
    ls2[part*2+1][li] = h2_as_u32(__floats2half2_rn(v.z, v.w));
  }
  __syncthreads();

  const int lx = tid & 15, ly = tid >> 4;
  const int ctr = (ly+1)*LROW + (lx+1);

  // ---- perception in packed f16; results held in 32 u32 regs (constant-indexed) ----
  const __half2 two    = __float2half2_rn(2.0f);
  const __half2 eighth = __float2half2_rn(0.125f);
  const __half2 quart  = __float2half2_rn(0.25f);
  const __half2 neg4   = __float2half2_rn(-4.0f);
  u32 rid[8], rgx[8], rgy[8], rlp[8];
  #pragma unroll
  for (int cp = 0; cp < 8; ++cp){
    const u32* pl = ls2[cp];
    __half2 t00 = u32_as_h2(pl[ctr-LROW-1]), t01 = u32_as_h2(pl[ctr-LROW]), t02 = u32_as_h2(pl[ctr-LROW+1]);
    __half2 t10 = u32_as_h2(pl[ctr-1]),      t11 = u32_as_h2(pl[ctr]),      t12 = u32_as_h2(pl[ctr+1]);
    __half2 t20 = u32_as_h2(pl[ctr+LROW-1]), t21 = u32_as_h2(pl[ctr+LROW]), t22 = u32_as_h2(pl[ctr+LROW+1]);
    __half2 sR = __hfma2(two, t12, __hadd2(t02, t22));
    __half2 sL = __hfma2(two, t10, __hadd2(t00, t20));
    __half2 sB = __hfma2(two, t21, __hadd2(t20, t22));
    __half2 sT = __hfma2(two, t01, __hadd2(t00, t02));
    __half2 sC = __hadd2(__hadd2(t10, t12), __hadd2(t01, t21));
    rid[cp] = h2_as_u32(t11);
    rgx[cp] = h2_as_u32(__hmul2(__hsub2(sR, sL), eighth));
    rgy[cp] = h2_as_u32(__hmul2(__hsub2(sB, sT), eighth));
    rlp[cp] = h2_as_u32(__hmul2(__hfma2(neg4, t11, sC), quart));
  }
  __syncthreads();   // all stencil reads done; smem becomes pbuf

  {
    u32* pb32 = (u32*)pbuf;
    #pragma unroll
    for (int cp = 0; cp < 8; ++cp){
      pb32[tid*34 +      cp] = rid[cp];   // ch 0..15
      pb32[tid*34 +  8 + cp] = rgx[cp];   // ch 16..31
      pb32[tid*34 + 16 + cp] = rgy[cp];   // ch 32..47
      pb32[tid*34 + 24 + cp] = rlp[cp];   // ch 48..63
    }
  }
  // from here on, all LDS traffic is intra-wave (wave wv owns pixels 64wv..64wv+63)

  const int rowbase = wv*4;
  const _Float16* pb16 = (const _Float16*)pbuf;

  auto loadfrag = [&](int px, int choff) -> f16x8 {
    const _Float16* ar = pb16 + px*PROW + choff;
    f16x4 lo = *(const f16x4*)ar;
    f16x4 hi = *(const f16x4*)(ar + 4);
    return __builtin_shufflevector(lo, hi, 0,1,2,3,4,5,6,7);
  };

  // ---- layer 1 ----
  f32x4 C1[4][4];
  #pragma unroll
  for (int gi = 0; gi < 4; ++gi){
    int px = (rowbase+gi)*16 + mm;
    f16x8 a0 = loadfrag(px, quad*8);
    f16x8 a1 = loadfrag(px, 32 + quad*8);
    #pragma unroll
    for (int nc = 0; nc < 4; ++nc){
      f32x4 c; c[0]=bias1[nc]; c[1]=bias1[nc]; c[2]=bias1[nc]; c[3]=bias1[nc];
      c = __builtin_amdgcn_mfma_f32_16x16x32_f16(a0, Bf[nc],   c, 0,0,0);
      c = __builtin_amdgcn_mfma_f32_16x16x32_f16(a1, Bf[4+nc], c, 0,0,0);
      C1[gi][nc] = c;
    }
  }
  #pragma unroll
  for (int gi = 0; gi < 4; ++gi)
    #pragma unroll
    for (int nc = 0; nc < 4; ++nc)
      #pragma unroll
      for (int r = 0; r < 4; ++r)
        pbuf[((rowbase+gi)*16 + quad*4 + r)*PROW + nc*16 + mm] =
            __half_as_ushort(__float2half(fmaxf(C1[gi][nc][r], 0.0f)));

  // ---- layer 2 ----
  f32x4 C2[4][2];
  #pragma unroll
  for (int gi = 0; gi < 4; ++gi){
    int px = (rowbase+gi)*16 + mm;
    f16x8 a0 = loadfrag(px, quad*8);
    f16x8 a1 = loadfrag(px, 32 + quad*8);
    #pragma unroll
    for (int nc = 0; nc < 2; ++nc){
      f32x4 c; c[0]=bias2[nc]; c[1]=bias2[nc]; c[2]=bias2[nc]; c[3]=bias2[nc];
      c = __builtin_amdgcn_mfma_f32_16x16x32_f16(a0, Bf[8+nc],  c, 0,0,0);
      c = __builtin_amdgcn_mfma_f32_16x16x32_f16(a1, Bf[10+nc], c, 0,0,0);
      C2[gi][nc] = c;
    }
  }
  #pragma unroll
  for (int gi = 0; gi < 4; ++gi)
    #pragma unroll
    for (int nc = 0; nc < 2; ++nc)
      #pragma unroll
      for (int r = 0; r < 4; ++r)
        pbuf[((rowbase+gi)*16 + quad*4 + r)*PROW + nc*16 + mm] =
            __half_as_ushort(__float2half(fmaxf(C2[gi][nc][r], 0.0f)));

  // ---- heads (K=32, a0 only) ----
  f32x4 C3[4];
  #pragma unroll
  for (int gi = 0; gi < 4; ++gi){
    int px = (rowbase+gi)*16 + mm;
    f16x8 a0 = loadfrag(px, quad*8);
    f32x4 c; c[0]=biasH; c[1]=biasH; c[2]=biasH; c[3]=biasH;
    C3[gi] = __builtin_amdgcn_mfma_f32_16x16x32_f16(a0, Bf[12], c, 0,0,0);
  }
  __syncthreads();   // dsb rows overlap other waves' pbuf rows
  {
    float* dsb = (float*)smem;   // 256 x 17 f32
    #pragma unroll
    for (int gi = 0; gi < 4; ++gi)
      #pragma unroll
      for (int r = 0; r < 4; ++r)
        dsb[((rowbase+gi)*16 + quad*4 + r)*17 + mm] = C3[gi][r];
  }

  // ---- epilogue: exact f32 (sc re-read from global, L2-hot) ----
  const float* dsb = (const float*)smem;
  int seed = seedp[0];
  u32 K0 = 0u, K1 = (u32)seed;
  const int ygl = y0t + ly, xgl = x0t + lx;
  const u32 pix = ((u32)b*HH + ygl)*WW + xgl;
  u32 mbits = pbits(K0, K1, pix);
  float m = ((int)mbits >= 0) ? 1.0f : 0.0f;

  const float* scp = sb + ((size_t)(ygl*WW + xgl))*16;
  float4 s0 = *(const float4*)(scp+0),  s1 = *(const float4*)(scp+4);
  float4 s2 = *(const float4*)(scp+8),  s3 = *(const float4*)(scp+12);
  float sc[16] = {s0.x,s0.y,s0.z,s0.w, s1.x,s1.y,s1.z,s1.w,
                  s2.x,s2.y,s2.z,s2.w, s3.x,s3.y,s3.z,s3.w};
  float ds[16], ns[16];
  #pragma unroll
  for (int ch = 0; ch < 16; ++ch) ds[ch] = dsb[tid*17 + ch];
  ds[3] = 0.0f; ds[6] = 0.0f; ds[7] = 0.0f;   // zero heads (cols were zero anyway)
  #pragma unroll
  for (int ch = 0; ch < 16; ++ch) ns[ch] = sc[ch] + ds[ch]*m;

  ns[4] = 0.95f * fminf(fmaxf(ns[4], -1.0f), 1.0f);
  ns[5] = 0.95f * fminf(fmaxf(ns[5], -1.0f), 1.0f);
  ns[0] = fminf(fmaxf(ns[0], 0.0f), 1.0f);
  ns[1] = fminf(fmaxf(ns[1], 0.0f), 1.0f);
  ns[2] = fminf(fmaxf(ns[2], 0.0f), 1.0f);
  ns[3] = sc[3];

  float* __restrict__ op = out + (size_t)pix*16;
  *(float4*)(op+ 0) = make_float4(ns[0],ns[1],ns[2],ns[3]);
  *(float4*)(op+ 4) = make_float4(ns[4],ns[5],ns[6],ns[7]);
  *(float4*)(op+ 8) = make_float4(ns[8],ns[9],ns[10],ns[11]);
  *(float4*)(op+12) = make_float4(ns[12],ns[13],ns[14],ns[15]);

  u32 k1a,k1b,k2a,k2b; noise_keys(seed, k1a,k1b,k2a,k2b);
  float vx = ns[4] + 0.2f*normal_from_bits(pbits(k1a,k1b,pix));
  float vy = ns[5] + 0.2f*normal_from_bits(pbits(k2a,k2b,pix));
  vxy[pix] = h2_as_u32(__floats2half2_rn(vx, vy));
  m0p[pix] = sc[3];
}

// ---------------- fused advect x2 + diffuse (halo-3 tile) ----------------
// |v| <= 0.95 + 0.2*5.6sigma ~ 2.07 -> per-step displacement <= 0.52 px < 1.
#define AT 32
__global__ __launch_bounds__(256) void advect_fused(
    const float* __restrict__ m0, const u32* __restrict__ vxy,
    float* __restrict__ out)
{
  __shared__ float sm0[38][39];
  __shared__ u32   sv [36][37];
  __shared__ float sm1[36][37];
  __shared__ float sm2[34][35];
  const int tid = threadIdx.x;
  const int X0 = blockIdx.x*AT, Y0 = blockIdx.y*AT, b = blockIdx.z;
  const size_t base = ((size_t)b) << 18;

  for (int t = tid; t < 38*38; t += 256){
    int ly = t/38, lx = t - ly*38;
    int gy = (Y0-3+ly)&511, gx = (X0-3+lx)&511;
    sm0[ly][lx] = m0[base + (gy<<9) + gx];
  }
  for (int t = tid; t < 36*36; t += 256){
    int ly = t/36, lx = t - ly*36;
    int gy = (Y0-2+ly)&511, gx = (X0-2+lx)&511;
    sv[ly][lx] = vxy[base + (gy<<9) + gx];
  }
  __syncthreads();

  // step 1: m1 on 36x36 (globals Y0-2..Y0+33)
  for (int t = tid; t < 36*36; t += 256){
    int ly = t/36, lx = t - ly*36;
    int gy = (Y0-2+ly)&511, gx = (X0-2+lx)&511;
    __half2 hv = u32_as_h2(sv[ly][lx]);
    float vx = __low2float(hv), vyv = __high2float(hv);
    float sy = (float)gy - vyv*0.25f;
    float sx = (float)gx - vx *0.25f;
    float y0f = floorf(sy), x0f = floorf(sx);
    float fy = sy - y0f, fx = sx - x0f;
    int l0y = (((int)y0f) - Y0 + 3) & 511;
    int l0x = (((int)x0f) - X0 + 3) & 511;
    float m00 = sm0[l0y][l0x],   m01 = sm0[l0y][l0x+1];
    float m10 = sm0[l0y+1][l0x], m11 = sm0[l0y+1][l0x+1];
    sm1[ly][lx] = (1.0f-fy)*((1.0f-fx)*m00 + fx*m01) + fy*((1.0f-fx)*m10 + fx*m11);
  }
  __syncthreads();

  // step 2: m2 on 34x34 (globals Y0-1..Y0+32); v local = +1
  for (int t = tid; t < 34*34; t += 256){
    int ly = t/34, lx = t - ly*34;
    int gy = (Y0-1+ly)&511, gx = (X0-1+lx)&511;
    __half2 hv = u32_as_h2(sv[ly+1][lx+1]);
    float vx = __low2float(hv), vyv = __high2float(hv);
    float sy = (float)gy - vyv*0.25f;
    float sx = (float)gx - vx *0.25f;
    float y0f = floorf(sy), x0f = floorf(sx);
    float fy = sy - y0f, fx = sx - x0f;
    int l0y = (((int)y0f) - Y0 + 2) & 511;
    int l0x = (((int)x0f) - X0 + 2) & 511;
    float m00 = sm1[l0y][l0x],   m01 = sm1[l0y][l0x+1];
    float m10 = sm1[l0y+1][l0x], m11 = sm1[l0y+1][l0x+1];
    sm2[ly][lx] = (1.0f-fy)*((1.0f-fx)*m00 + fx*m01) + fy*((1.0f-fx)*m10 + fx*m11);
  }
  __syncthreads();

  // diffuse 32x32 -> out ch3
  for (int t = tid; t < 32*32; t += 256){
    int ly = t >> 5, lx = t & 31;
    int gy = Y0 + ly, gx = X0 + lx;
    float c = sm2[ly+1][lx+1];
    float r = sm2[ly+1][lx+2], l = sm2[ly+1][lx];
    float d = sm2[ly+2][lx+1], u = sm2[ly][lx+1];
    out[(base + (gy<<9) + gx)*16 + 3] = c + 0.05f*((r+l+d+u)*0.25f - c);
  }
}

// ---------------- launch ----------------
extern "C" void kernel_launch(void* const* d_in, const int* in_sizes, int n_in,
                              void* d_out, int out_size, void* d_ws, size_t ws_size,
                              hipStream_t stream)
{
  const float* st   = (const float*)d_in[0];
  const int*   seed = (const int*)  d_in[1];
  const float* w1   = (const float*)d_in[2];
  const float* b1   = (const float*)d_in[3];
  const float* w2   = (const float*)d_in[4];
  const float* b2   = (const float*)d_in[5];
  const float* wrgb = (const float*)d_in[6];
  const float* brgb = (const float*)d_in[7];
  const float* wvel = (const float*)d_in[8];
  const float* bvel = (const float*)d_in[9];
  const float* whid = (const float*)d_in[10];
  const float* bhid = (const float*)d_in[11];
  float* out = (float*)d_out;

  const int npix = NB*HH*WW;                 // 2^21
  float* m0p = (float*)d_ws;                 // 8 MB
  u32*   vxy = (u32*)(m0p + npix);           // 8 MB
  unsigned short* wfrag = (unsigned short*)(vxy + npix);  // 13312 B
  float* bcat = (float*)(wfrag + 13*64*8);   // 64 B

  prep_w<<<1, 256, 0, stream>>>(w1, w2, wrgb, wvel, whid, brgb, bvel, bhid, wfrag, bcat);

  dim3 gridA(WW/TS, HH/TS, NB);
  nca_main<<<gridA, 256, 0, stream>>>(st, seed, b1, b2, wfrag, bcat, out, vxy, m0p);

  dim3 gridB(WW/AT, HH/AT, NB);
  advect_fused<<<gridB, 256, 0, stream>>>(m0p, vxy, out);
}